// Round 1
// baseline (148.616 us; speedup 1.0000x reference)
//
#include <hip/hip_runtime.h>

// YOLO loss: per-cell masked squared-error reduction.
// Inputs: label_pre [B,7,7,30] fp32, label_ground_truth [B,7,7,30] fp32.
// Per cell: mask = (gt[...,4] == 1.0)
//   per_cell = mask ? 5*sum((pre[0:4]-gt[0:4])^2) + 10*(pre[4]-gt[4])^2
//                   : 0.5*(pre[4]-gt[4])^2
// Output: scalar sum, shape (1,).

__global__ __launch_bounds__(256) void yolo_loss_kernel(
    const float* __restrict__ pre,
    const float* __restrict__ gt,
    float* __restrict__ out,
    long long n_cells)
{
    long long tid    = (long long)blockIdx.x * blockDim.x + threadIdx.x;
    long long stride = (long long)gridDim.x * blockDim.x;

    float acc = 0.0f;
    for (long long cell = tid; cell < n_cells; cell += stride) {
        long long base = cell * 30;  // cell*30 is even -> 8B-aligned float2 loads
        float2 p01 = *reinterpret_cast<const float2*>(pre + base);
        float2 p23 = *reinterpret_cast<const float2*>(pre + base + 2);
        float  pc  = pre[base + 4];
        float2 g01 = *reinterpret_cast<const float2*>(gt + base);
        float2 g23 = *reinterpret_cast<const float2*>(gt + base + 2);
        float  gc  = gt[base + 4];

        float d0 = p01.x - g01.x;
        float d1 = p01.y - g01.y;
        float d2 = p23.x - g23.x;
        float d3 = p23.y - g23.y;
        float coord = d0 * d0 + d1 * d1 + d2 * d2 + d3 * d3;
        float dc = pc - gc;
        float conf = dc * dc;

        acc += (gc == 1.0f) ? fmaf(5.0f, coord, 10.0f * conf) : 0.5f * conf;
    }

    // wave-64 butterfly-free shuffle-down reduction
    for (int off = 32; off > 0; off >>= 1)
        acc += __shfl_down(acc, off, 64);

    __shared__ float s[4];
    int lane = threadIdx.x & 63;
    int wid  = threadIdx.x >> 6;
    if (lane == 0) s[wid] = acc;
    __syncthreads();

    if (threadIdx.x == 0) {
        float total = s[0] + s[1] + s[2] + s[3];
        atomicAdd(out, total);  // device-scope by default on CDNA
    }
}

extern "C" void kernel_launch(void* const* d_in, const int* in_sizes, int n_in,
                              void* d_out, int out_size, void* d_ws, size_t ws_size,
                              hipStream_t stream) {
    const float* pre = (const float*)d_in[0];
    const float* gt  = (const float*)d_in[1];
    float* out = (float*)d_out;

    // d_out is poisoned once and never re-poisoned between replays: zero it
    // ourselves every call (stream op — graph-capture safe).
    hipMemsetAsync(out, 0, sizeof(float), stream);

    long long n_cells = (long long)in_sizes[0] / 30;  // 65536*7*7 = 3,211,264

    const int block = 256;
    const int grid  = 2048;  // grid-stride; ~6.1 cells/thread
    yolo_loss_kernel<<<grid, block, 0, stream>>>(pre, gt, out, n_cells);
}

// Round 2
// 139.762 us; speedup vs baseline: 1.0633x; 1.0633x over previous
//
#include <hip/hip_runtime.h>

// YOLO loss: per-cell masked squared-error reduction.
// Inputs: label_pre [B,7,7,30] fp32, label_ground_truth [B,7,7,30] fp32.
// Per cell: mask = (gt[...,4] == 1.0)
//   per_cell = mask ? 5*sum((pre[0:4]-gt[0:4])^2) + 10*(pre[4]-gt[4])^2
//                   : 0.5*(pre[4]-gt[4])^2
// Output: scalar sum, shape (1,).
//
// Layout trick: per 2-cell period (60 floats = 15 aligned float4 chunks),
// the needed channels (0..4 of each cell) live in exactly 4 chunks at
// offsets {0,1,7,8}:
//   chunk +0: cell0 coords 0-3              (comps 0-3)
//   chunk +1: cell0 conf                    (comp 0)
//   chunk +7: cell1 coords 0,1              (comps 2,3)
//   chunk +8: cell1 coords 2,3 + conf       (comps 0,1,2)
// One lane per needed chunk; the cross-chunk mask (gt conf) comes from the
// adjacent lane via __shfl_down(...,1). Role pairs (m%4 = 0/1 and 2/3) never
// straddle a wave boundary (64 % 4 == 0).

__global__ __launch_bounds__(256) void yolo_loss_kernel(
    const float* __restrict__ pre,
    const float* __restrict__ gt,
    float* __restrict__ out,
    long long total_chunks)   // n_cell_pairs * 4
{
    const int role = threadIdx.x & 3;
    // role -> chunk offset within the 15-chunk period: 0,1,7,8
    const int off = (role & 1) + ((role & 2) ? 7 : 0);

    long long tid    = (long long)blockIdx.x * blockDim.x + threadIdx.x;
    long long stride = (long long)gridDim.x * blockDim.x;   // multiple of 4

    float acc = 0.0f;
    for (long long m = tid; m < total_chunks; m += stride) {
        long long q = (m >> 2) * 15 + off;           // float4 chunk index
        const float4 p = *reinterpret_cast<const float4*>(pre + q * 4);
        const float4 g = *reinterpret_cast<const float4*>(gt  + q * 4);

        float d0 = p.x - g.x;
        float d1 = p.y - g.y;
        float d2 = p.z - g.z;
        float d3 = p.w - g.w;

        // neighbor lane's gt values (conf channels live one lane up)
        float gxn = __shfl_down(g.x, 1);   // role0 needs role1's g.x (cell0 conf)
        float gzn = __shfl_down(g.z, 1);   // role2 needs role3's g.z (cell1 conf)

        float c;
        if (role == 0) {
            // cell0 coords 0-3
            c = (gxn == 1.0f) ? 5.0f * (d0*d0 + d1*d1 + d2*d2 + d3*d3) : 0.0f;
        } else if (role == 1) {
            // cell0 conf (local)
            c = (g.x == 1.0f) ? 10.0f * d0*d0 : 0.5f * d0*d0;
        } else if (role == 2) {
            // cell1 coords 0,1 (comps 2,3)
            c = (gzn == 1.0f) ? 5.0f * (d2*d2 + d3*d3) : 0.0f;
        } else {
            // cell1 coords 2,3 (comps 0,1) + conf (comp 2, local)
            c = (g.z == 1.0f) ? 5.0f * (d0*d0 + d1*d1) + 10.0f * d2*d2
                              : 0.5f * d2*d2;
        }
        acc += c;
    }

    // wave-64 shuffle-down reduction
    for (int offr = 32; offr > 0; offr >>= 1)
        acc += __shfl_down(acc, offr, 64);

    __shared__ float s[4];
    int lane = threadIdx.x & 63;
    int wid  = threadIdx.x >> 6;
    if (lane == 0) s[wid] = acc;
    __syncthreads();

    if (threadIdx.x == 0) {
        float total = s[0] + s[1] + s[2] + s[3];
        atomicAdd(out, total);   // device-scope by default on CDNA
    }
}

extern "C" void kernel_launch(void* const* d_in, const int* in_sizes, int n_in,
                              void* d_out, int out_size, void* d_ws, size_t ws_size,
                              hipStream_t stream) {
    const float* pre = (const float*)d_in[0];
    const float* gt  = (const float*)d_in[1];
    float* out = (float*)d_out;

    // d_out is poisoned once and never re-poisoned between replays: zero it
    // ourselves every call (stream op — graph-capture safe).
    hipMemsetAsync(out, 0, sizeof(float), stream);

    long long n_cells = (long long)in_sizes[0] / 30;   // 65536*7*7 = 3,211,264 (even)
    long long total_chunks = (n_cells / 2) * 4;        // 4 needed chunks per cell pair

    const int block = 256;
    const int grid  = 2048;
    yolo_loss_kernel<<<grid, block, 0, stream>>>(pre, gt, out, total_chunks);
}